// Round 1
// baseline (329.878 us; speedup 1.0000x reference)
//
#include <hip/hip_runtime.h>
#include <hip/hip_bf16.h>
#include <stdint.h>

#define NN 8192
#define FIN 512
#define FOUT 256
#define ALPHAV 0.2f
#define MASKF 9e-15f
#define L2E 1.44269504088896340736f

typedef __attribute__((ext_vector_type(8))) short bf16x8;
typedef __attribute__((ext_vector_type(4))) float f32x4;

static __device__ __forceinline__ float ex2(float x){
#if __has_builtin(__builtin_amdgcn_exp2f)
  return __builtin_amdgcn_exp2f(x);
#else
  return exp2f(x);
#endif
}
static __device__ __forceinline__ unsigned short f2bf(float f){
  __bf16 b = (__bf16)f;
  return __builtin_bit_cast(unsigned short, b);
}

// ---------------- K1: h = x @ W (fp32), also emit hT (bf16, transposed) ----
__global__ __launch_bounds__(128) void k_gemm_h(
    const float* __restrict__ x, const float* __restrict__ Wm,
    float* __restrict__ h, unsigned short* __restrict__ hT)
{
  __shared__ __align__(16) float As[16][32];    // [kk][i] transposed
  __shared__ __align__(16) float Bs[16][256];   // [kk][n]
  const int t  = threadIdx.x;
  const int wv = t >> 6;          // 0..1, wave handles 16 rows
  const int tx = t & 63;          // col group (4 cols)
  const int i0 = blockIdx.x * 32;

  float acc[16][4];
#pragma unroll
  for (int r = 0; r < 16; ++r)
#pragma unroll
    for (int c = 0; c < 4; ++c) acc[r][c] = 0.f;

  const int ai = t >> 2;          // 0..31 row for A load
  const int ak = (t & 3) * 4;     // k offset
  const int bk = t >> 3;          // 0..15 row for B load
  const int bc = (t & 7) * 32;    // col base

  for (int k0 = 0; k0 < FIN; k0 += 16) {
    float4 xv = *(const float4*)(x + (size_t)(i0 + ai) * FIN + k0 + ak);
    __syncthreads();
    As[ak + 0][ai] = xv.x;
    As[ak + 1][ai] = xv.y;
    As[ak + 2][ai] = xv.z;
    As[ak + 3][ai] = xv.w;
#pragma unroll
    for (int q = 0; q < 8; ++q) {
      float4 wv4 = *(const float4*)(Wm + (size_t)(k0 + bk) * FOUT + bc + q * 4);
      *(float4*)(&Bs[bk][bc + q * 4]) = wv4;
    }
    __syncthreads();
#pragma unroll
    for (int kk = 0; kk < 16; ++kk) {
      float4 bv = *(const float4*)(&Bs[kk][tx * 4]);
      float bb[4] = {bv.x, bv.y, bv.z, bv.w};
      float aa[16];
#pragma unroll
      for (int q = 0; q < 4; ++q) {
        float4 av = *(const float4*)(&As[kk][wv * 16 + q * 4]);
        aa[q*4+0] = av.x; aa[q*4+1] = av.y; aa[q*4+2] = av.z; aa[q*4+3] = av.w;
      }
#pragma unroll
      for (int r = 0; r < 16; ++r)
#pragma unroll
        for (int c = 0; c < 4; ++c) acc[r][c] = fmaf(aa[r], bb[c], acc[r][c]);
    }
  }
  // h fp32
#pragma unroll
  for (int r = 0; r < 16; ++r) {
    int i = i0 + wv * 16 + r;
    float4 o; o.x = acc[r][0]; o.y = acc[r][1]; o.z = acc[r][2]; o.w = acc[r][3];
    *(float4*)(h + (size_t)i * FOUT + tx * 4) = o;
  }
  // hT bf16 (transposed): 4 consecutive rows per 8B store
#pragma unroll
  for (int c = 0; c < 4; ++c) {
    int n = tx * 4 + c;
#pragma unroll
    for (int q = 0; q < 4; ++q) {
      ushort4 u;
      u.x = f2bf(acc[q * 4 + 0][c]);
      u.y = f2bf(acc[q * 4 + 1][c]);
      u.z = f2bf(acc[q * 4 + 2][c]);
      u.w = f2bf(acc[q * 4 + 3][c]);
      *(ushort4*)(hT + (size_t)n * NN + i0 + wv * 16 + q * 4) = u;
    }
  }
}

// ---------------- K2: f1 = h@a1, f2 = h@a2 (one wave per row) -------------
__global__ __launch_bounds__(256) void k_f12(
    const float* __restrict__ h, const float* __restrict__ aG,
    float* __restrict__ f1, float* __restrict__ f2)
{
  const int t = threadIdx.x;
  const int wv = t >> 6;
  const int l = t & 63;
  const int i = blockIdx.x * 4 + wv;
  float4 hv = *(const float4*)(h + (size_t)i * FOUT + l * 4);
  float4 a1 = *(const float4*)(aG + l * 4);
  float4 a2 = *(const float4*)(aG + FOUT + l * 4);
  float s1 = hv.x * a1.x + hv.y * a1.y + hv.z * a1.z + hv.w * a1.w;
  float s2 = hv.x * a2.x + hv.y * a2.y + hv.z * a2.z + hv.w * a2.w;
#pragma unroll
  for (int off = 32; off > 0; off >>= 1) {
    s1 += __shfl_xor(s1, off);
    s2 += __shfl_xor(s2, off);
  }
  if (l == 0) { f1[i] = s1; f2[i] = s2; }
}

// ---------------- K3: per-row max + exp-sum + adj->bitmask ----------------
__global__ __launch_bounds__(256) void k_rowstat(
    const int* __restrict__ adj, const float* __restrict__ f1,
    const float* __restrict__ f2, unsigned long long* __restrict__ maskg,
    float* __restrict__ row_m, float* __restrict__ row_inv)
{
  __shared__ float red[8];
  const int i = blockIdx.x;
  const int t = threadIdx.x;
  const int wv = t >> 6;
  const int l = t & 63;
  const float f1i = f1[i];
  const int* arow = adj + (size_t)i * NN + wv * 2048;
  const float* f2w = f2 + wv * 2048;
  unsigned int bits = 0;
  float mloc = -3.0e38f;
  float f2loc[32];
#pragma unroll
  for (int it = 0; it < 32; ++it) {
    int av = arow[it * 64 + l];
    bool bit = av > 0;
    unsigned long long bal = __ballot(bit);
    if (l == 0) maskg[(size_t)i * 128 + wv * 32 + it] = bal;
    float f2j = f2w[it * 64 + l];
    f2loc[it] = f2j;
    float s = f1i + f2j;
    float ls = fmaxf(s, ALPHAV * s);
    float e = bit ? ls : MASKF;
    mloc = fmaxf(mloc, e);
    bits |= (bit ? 1u : 0u) << it;
  }
#pragma unroll
  for (int off = 32; off > 0; off >>= 1) mloc = fmaxf(mloc, __shfl_xor(mloc, off));
  if (l == 0) red[wv] = mloc;
  __syncthreads();
  const float m = fmaxf(fmaxf(red[0], red[1]), fmaxf(red[2], red[3]));
  const float nm = -m * L2E;
  const float cm = ex2(fmaf(MASKF, L2E, nm));
  float sl = 0.f;
#pragma unroll
  for (int it = 0; it < 32; ++it) {
    float s = f1i + f2loc[it];
    float ls = fmaxf(s, ALPHAV * s);
    float pe = ex2(fmaf(ls, L2E, nm));
    sl += ((bits >> it) & 1u) ? pe : cm;
  }
#pragma unroll
  for (int off = 32; off > 0; off >>= 1) sl += __shfl_xor(sl, off);
  __syncthreads();
  if (l == 0) red[4 + wv] = sl;
  __syncthreads();
  if (t == 0) {
    float tot = red[4] + red[5] + red[6] + red[7];
    row_m[i] = m;
    row_inv[i] = 1.f / tot;
  }
}

// ---------------- K4: fused P-regen + (P @ h) via bf16 MFMA ---------------
// grid (64, 4): bx = 128-row block, ks = K-split quarter (2048 cols of j)
__global__ __launch_bounds__(256, 2) void k_spmm(
    const unsigned short* __restrict__ hTg,
    const unsigned long long* __restrict__ maskg,
    const float* __restrict__ f1, const float* __restrict__ f2,
    const float* __restrict__ row_m,
    float* __restrict__ outp, float* __restrict__ part)
{
  __shared__ __align__(16) unsigned short hTs[256 * 64]; // hT tile [n][kk] XOR-swizzled
  const int t = threadIdx.x;
  const int wv = t >> 6;
  const int l = t & 63;
  const int lg = l >> 4;
  const int lm = l & 15;
  const int bx = blockIdx.x;
  const int ks = blockIdx.y;
  const int r0 = bx * 128 + wv * 32;   // wave owns 32 rows (2 A-frags)

  float f1r[2], nmv[2], cmv[2];
  const unsigned long long* mrow[2];
#pragma unroll
  for (int af = 0; af < 2; ++af) {
    int r = r0 + af * 16 + lm;
    f1r[af] = f1[r];
    float mr = row_m[r];
    nmv[af] = -mr * L2E;
    cmv[af] = ex2(fmaf(MASKF, L2E, nmv[af]));
    mrow[af] = maskg + (size_t)r * 128 + ks * 32;
  }

  f32x4 accA[16], accB[16];
#pragma unroll
  for (int nf = 0; nf < 16; ++nf) {
#pragma unroll
    for (int e = 0; e < 4; ++e) { accA[nf][e] = 0.f; accB[nf][e] = 0.f; }
  }

  const int sn  = t >> 3;        // staging row within 32-row group
  const int skb = (t & 7) * 8;   // staging k offset (8 bf16 = 16B)

  for (int jt = 0; jt < 32; ++jt) {
    const int jbase = ks * 2048 + jt * 64;
    unsigned long long w64a = mrow[0][jt];
    unsigned long long w64b = mrow[1][jt];
#pragma unroll
    for (int c = 0; c < 8; ++c) {
      int n = c * 32 + sn;
      uint4 v = *(const uint4*)(hTg + (size_t)n * NN + jbase + skb);
      *(uint4*)(&hTs[n * 64 + (skb ^ ((n & 7) << 3))]) = v;
    }
    __syncthreads();
#pragma unroll
    for (int k32 = 0; k32 < 2; ++k32) {
      const int kb = k32 * 32 + lg * 8;
      float4 fA = *(const float4*)(f2 + jbase + kb);
      float4 fB = *(const float4*)(f2 + jbase + kb + 4);
      float fv[8] = {fA.x, fA.y, fA.z, fA.w, fB.x, fB.y, fB.z, fB.w};
      bf16x8 afr0, afr1;
      unsigned byA = (unsigned)(w64a >> kb) & 0xffu;
      unsigned byB = (unsigned)(w64b >> kb) & 0xffu;
#pragma unroll
      for (int b = 0; b < 8; ++b) {
        float s0 = f1r[0] + fv[b];
        float t0 = fmaxf(s0, ALPHAV * s0);
        float p0 = ex2(fmaf(t0, L2E, nmv[0]));
        p0 = (byA & (1u << b)) ? p0 : cmv[0];
        afr0[b] = (short)f2bf(p0);
        float s1 = f1r[1] + fv[b];
        float t1 = fmaxf(s1, ALPHAV * s1);
        float p1 = ex2(fmaf(t1, L2E, nmv[1]));
        p1 = (byB & (1u << b)) ? p1 : cmv[1];
        afr1[b] = (short)f2bf(p1);
      }
#pragma unroll
      for (int nf = 0; nf < 16; ++nf) {
        int n = nf * 16 + lm;
        int addr = n * 64 + ((k32 * 32 + lg * 8) ^ ((n & 7) << 3));
        bf16x8 bb = *(const bf16x8*)(&hTs[addr]);
        accA[nf] = __builtin_amdgcn_mfma_f32_16x16x32_bf16(afr0, bb, accA[nf], 0, 0, 0);
        accB[nf] = __builtin_amdgcn_mfma_f32_16x16x32_bf16(afr1, bb, accB[nf], 0, 0, 0);
      }
    }
    __syncthreads();
  }

  float* dst = (ks == 0) ? outp : (part + (size_t)(ks - 1) * NN * FOUT);
#pragma unroll
  for (int nf = 0; nf < 16; ++nf) {
    int col = nf * 16 + lm;
#pragma unroll
    for (int e = 0; e < 4; ++e) {
      int rowA = r0 + lg * 4 + e;
      int rowB = r0 + 16 + lg * 4 + e;
      dst[(size_t)rowA * FOUT + col] = accA[nf][e];
      dst[(size_t)rowB * FOUT + col] = accB[nf][e];
    }
  }
}

// ---------------- K5: sum K-partials, scale by 1/rowsum -------------------
__global__ __launch_bounds__(256) void k_fin(
    float* __restrict__ outp, const float* __restrict__ part,
    const float* __restrict__ row_inv)
{
  const int idx4 = blockIdx.x * 256 + threadIdx.x;
  const size_t e = (size_t)idx4 * 4;
  const int i = (int)(e >> 8);
  float4 o  = *(float4*)(outp + e);
  float4 p0 = *(const float4*)(part + e);
  float4 p1 = *(const float4*)(part + (size_t)NN * FOUT + e);
  float4 p2 = *(const float4*)(part + 2 * (size_t)NN * FOUT + e);
  float inv = row_inv[i];
  o.x = (o.x + p0.x + p1.x + p2.x) * inv;
  o.y = (o.y + p0.y + p1.y + p2.y) * inv;
  o.z = (o.z + p0.z + p1.z + p2.z) * inv;
  o.w = (o.w + p0.w + p1.w + p2.w) * inv;
  *(float4*)(outp + e) = o;
}

extern "C" void kernel_launch(void* const* d_in, const int* in_sizes, int n_in,
                              void* d_out, int out_size, void* d_ws, size_t ws_size,
                              hipStream_t stream)
{
  const float* x  = (const float*)d_in[0];
  const int* adj  = (const int*)d_in[1];
  const float* Wm = (const float*)d_in[2];
  const float* aG = (const float*)d_in[3];
  float* outp = (float*)d_out;

  char* w = (char*)d_ws;
  float* h             = (float*)(w + 0);                    // 8 MB
  unsigned short* hT   = (unsigned short*)(w + 8388608);     // 4 MB
  float* f1            = (float*)(w + 12582912);             // 32 KB
  float* f2            = (float*)(w + 12615680);             // 32 KB
  float* row_m         = (float*)(w + 12648448);             // 32 KB
  float* row_inv       = (float*)(w + 12681216);             // 32 KB
  unsigned long long* maskg = (unsigned long long*)(w + 12713984); // 8 MB
  float* part          = (float*)(w + 21102592);             // 24 MB (3 partials)

  hipLaunchKernelGGL(k_gemm_h,  dim3(256),    dim3(128), 0, stream, x, Wm, h, hT);
  hipLaunchKernelGGL(k_f12,     dim3(2048),   dim3(256), 0, stream, h, aG, f1, f2);
  hipLaunchKernelGGL(k_rowstat, dim3(8192),   dim3(256), 0, stream, adj, f1, f2, maskg, row_m, row_inv);
  hipLaunchKernelGGL(k_spmm,    dim3(64, 4),  dim3(256), 0, stream, hT, maskg, f1, f2, row_m, outp, part);
  hipLaunchKernelGGL(k_fin,     dim3(2048),   dim3(256), 0, stream, outp, part, row_inv);
}

// Round 2
// 257.596 us; speedup vs baseline: 1.2806x; 1.2806x over previous
//
#include <hip/hip_runtime.h>
#include <hip/hip_bf16.h>
#include <stdint.h>

#define NN 8192
#define FIN 512
#define FOUT 256
#define ALPHAV 0.2f
#define MASKF 9e-15f
#define L2E 1.44269504088896340736f

typedef __attribute__((ext_vector_type(8))) short bf16x8;
typedef __attribute__((ext_vector_type(4))) float f32x4;

static __device__ __forceinline__ float ex2(float x){
#if __has_builtin(__builtin_amdgcn_exp2f)
  return __builtin_amdgcn_exp2f(x);
#else
  return exp2f(x);
#endif
}
static __device__ __forceinline__ unsigned short f2bf(float f){
  __bf16 b = (__bf16)f;
  return __builtin_bit_cast(unsigned short, b);
}

// ---------------- K1: h = x @ W (fp32), also emit hT (bf16, transposed) ----
__global__ __launch_bounds__(128) void k_gemm_h(
    const float* __restrict__ x, const float* __restrict__ Wm,
    float* __restrict__ h, unsigned short* __restrict__ hT)
{
  __shared__ __align__(16) float As[16][32];    // [kk][i] transposed
  __shared__ __align__(16) float Bs[16][256];   // [kk][n]
  const int t  = threadIdx.x;
  const int wv = t >> 6;          // 0..1, wave handles 16 rows
  const int tx = t & 63;          // col group (4 cols)
  const int i0 = blockIdx.x * 32;

  float acc[16][4];
#pragma unroll
  for (int r = 0; r < 16; ++r)
#pragma unroll
    for (int c = 0; c < 4; ++c) acc[r][c] = 0.f;

  const int ai = t >> 2;          // 0..31 row for A load
  const int ak = (t & 3) * 4;     // k offset
  const int bk = t >> 3;          // 0..15 row for B load
  const int bc = (t & 7) * 32;    // col base

  for (int k0 = 0; k0 < FIN; k0 += 16) {
    float4 xv = *(const float4*)(x + (size_t)(i0 + ai) * FIN + k0 + ak);
    __syncthreads();
    As[ak + 0][ai] = xv.x;
    As[ak + 1][ai] = xv.y;
    As[ak + 2][ai] = xv.z;
    As[ak + 3][ai] = xv.w;
#pragma unroll
    for (int q = 0; q < 8; ++q) {
      float4 wv4 = *(const float4*)(Wm + (size_t)(k0 + bk) * FOUT + bc + q * 4);
      *(float4*)(&Bs[bk][bc + q * 4]) = wv4;
    }
    __syncthreads();
#pragma unroll
    for (int kk = 0; kk < 16; ++kk) {
      float4 bv = *(const float4*)(&Bs[kk][tx * 4]);
      float bb[4] = {bv.x, bv.y, bv.z, bv.w};
      float aa[16];
#pragma unroll
      for (int q = 0; q < 4; ++q) {
        float4 av = *(const float4*)(&As[kk][wv * 16 + q * 4]);
        aa[q*4+0] = av.x; aa[q*4+1] = av.y; aa[q*4+2] = av.z; aa[q*4+3] = av.w;
      }
#pragma unroll
      for (int r = 0; r < 16; ++r)
#pragma unroll
        for (int c = 0; c < 4; ++c) acc[r][c] = fmaf(aa[r], bb[c], acc[r][c]);
    }
  }
  // h fp32
#pragma unroll
  for (int r = 0; r < 16; ++r) {
    int i = i0 + wv * 16 + r;
    float4 o; o.x = acc[r][0]; o.y = acc[r][1]; o.z = acc[r][2]; o.w = acc[r][3];
    *(float4*)(h + (size_t)i * FOUT + tx * 4) = o;
  }
  // hT bf16 (transposed): 4 consecutive rows per 8B store
#pragma unroll
  for (int c = 0; c < 4; ++c) {
    int n = tx * 4 + c;
#pragma unroll
    for (int q = 0; q < 4; ++q) {
      ushort4 u;
      u.x = f2bf(acc[q * 4 + 0][c]);
      u.y = f2bf(acc[q * 4 + 1][c]);
      u.z = f2bf(acc[q * 4 + 2][c]);
      u.w = f2bf(acc[q * 4 + 3][c]);
      *(ushort4*)(hT + (size_t)n * NN + i0 + wv * 16 + q * 4) = u;
    }
  }
}

// ---------------- K2: f1 = h@a1, f2 = h@a2 (one wave per row) -------------
__global__ __launch_bounds__(256) void k_f12(
    const float* __restrict__ h, const float* __restrict__ aG,
    float* __restrict__ f1, float* __restrict__ f2)
{
  const int t = threadIdx.x;
  const int wv = t >> 6;
  const int l = t & 63;
  const int i = blockIdx.x * 4 + wv;
  float4 hv = *(const float4*)(h + (size_t)i * FOUT + l * 4);
  float4 a1 = *(const float4*)(aG + l * 4);
  float4 a2 = *(const float4*)(aG + FOUT + l * 4);
  float s1 = hv.x * a1.x + hv.y * a1.y + hv.z * a1.z + hv.w * a1.w;
  float s2 = hv.x * a2.x + hv.y * a2.y + hv.z * a2.z + hv.w * a2.w;
#pragma unroll
  for (int off = 32; off > 0; off >>= 1) {
    s1 += __shfl_xor(s1, off);
    s2 += __shfl_xor(s2, off);
  }
  if (l == 0) { f1[i] = s1; f2[i] = s2; }
}

// ---------------- K3: per-row max + exp-sum + adj->bitmask ----------------
__global__ __launch_bounds__(256) void k_rowstat(
    const int* __restrict__ adj, const float* __restrict__ f1,
    const float* __restrict__ f2, unsigned long long* __restrict__ maskg,
    float* __restrict__ row_m, float* __restrict__ row_inv)
{
  __shared__ float red[8];
  const int i = blockIdx.x;
  const int t = threadIdx.x;
  const int wv = t >> 6;
  const int l = t & 63;
  const float f1i = f1[i];
  const int* arow = adj + (size_t)i * NN + wv * 2048;
  const float* f2w = f2 + wv * 2048;
  unsigned int bits = 0;
  float mloc = -3.0e38f;
  float f2loc[32];
#pragma unroll
  for (int it = 0; it < 32; ++it) {
    int av = arow[it * 64 + l];
    bool bit = av > 0;
    unsigned long long bal = __ballot(bit);
    if (l == 0) maskg[(size_t)i * 128 + wv * 32 + it] = bal;
    float f2j = f2w[it * 64 + l];
    f2loc[it] = f2j;
    float s = f1i + f2j;
    float ls = fmaxf(s, ALPHAV * s);
    float e = bit ? ls : MASKF;
    mloc = fmaxf(mloc, e);
    bits |= (bit ? 1u : 0u) << it;
  }
#pragma unroll
  for (int off = 32; off > 0; off >>= 1) mloc = fmaxf(mloc, __shfl_xor(mloc, off));
  if (l == 0) red[wv] = mloc;
  __syncthreads();
  const float m = fmaxf(fmaxf(red[0], red[1]), fmaxf(red[2], red[3]));
  const float nm = -m * L2E;
  const float cm = ex2(fmaf(MASKF, L2E, nm));
  float sl = 0.f;
#pragma unroll
  for (int it = 0; it < 32; ++it) {
    float s = f1i + f2loc[it];
    float ls = fmaxf(s, ALPHAV * s);
    float pe = ex2(fmaf(ls, L2E, nm));
    sl += ((bits >> it) & 1u) ? pe : cm;
  }
#pragma unroll
  for (int off = 32; off > 0; off >>= 1) sl += __shfl_xor(sl, off);
  __syncthreads();
  if (l == 0) red[4 + wv] = sl;
  __syncthreads();
  if (t == 0) {
    float tot = red[4] + red[5] + red[6] + red[7];
    row_m[i] = m;
    row_inv[i] = 1.f / tot;
  }
}

// ---------------- K4: fused P-regen + (P @ h) via bf16 MFMA ---------------
// grid (64, 4, 2): bx = 128-row block, ks = K quarter (2048 j), cs = col half
// -> 512 blocks = 2 blocks/CU = 2 waves/SIMD; double-buffered LDS;
// global_load_lds(16B) staging with pre-swizzled source addresses
// (LDS dest linear, XOR swizzle folded into source k — bits 3-5 only,
// so each lane's 16B global read stays contiguous).
__global__ __launch_bounds__(256, 2) void k_spmm(
    const unsigned short* __restrict__ hTg,
    const unsigned long long* __restrict__ maskg,
    const float* __restrict__ f1, const float* __restrict__ f2,
    const float* __restrict__ row_m,
    float* __restrict__ outp, float* __restrict__ part)
{
  __shared__ __align__(16) unsigned short hTs[2][128 * 64]; // 2 x 16 KB
  const int t = threadIdx.x;
  const int wv = t >> 6;
  const int l = t & 63;
  const int lg = l >> 4;
  const int lm = l & 15;
  const int bx = blockIdx.x;
  const int ks = blockIdx.y;
  const int cs = blockIdx.z;
  const int r0 = bx * 128 + wv * 32;   // wave owns 32 rows (2 A-frags)
  const int krange0 = ks * 2048;

  float f1r[2], nmv[2], cmv[2];
  const unsigned long long* mrow[2];
#pragma unroll
  for (int af = 0; af < 2; ++af) {
    int r = r0 + af * 16 + lm;
    f1r[af] = f1[r];
    float mr = row_m[r];
    nmv[af] = -mr * L2E;
    cmv[af] = ex2(fmaf(MASKF, L2E, nmv[af]));
    mrow[af] = maskg + (size_t)r * 128 + ks * 32;
  }

  f32x4 accA[8], accB[8];
#pragma unroll
  for (int nf = 0; nf < 8; ++nf) {
#pragma unroll
    for (int e = 0; e < 4; ++e) { accA[nf][e] = 0.f; accB[nf][e] = 0.f; }
  }

  // staging geometry: chunk c, thread t -> LDS elements c*2048 + t*8 (linear)
  //   n_loc = c*32 + (t>>3), k_swz = (t&7)*8, src k = k_swz ^ ((n_loc&7)<<3)
  const int sn_base = t >> 3;                                   // 0..31
  const int sk      = ((t & 7) * 8) ^ (((t >> 3) & 7) << 3);    // 0..63
  const size_t grow0 = (size_t)(cs * 128 + sn_base) * NN + krange0 + sk;

#define STAGE(BUF, JT)                                                        \
  do {                                                                        \
    const int _jo = (JT) * 64;                                                \
    _Pragma("unroll")                                                         \
    for (int c = 0; c < 4; ++c) {                                             \
      const unsigned short* gp = hTg + grow0 + (size_t)c * 32 * NN + _jo;     \
      char* lp = ((char*)&hTs[BUF][0]) + c * 4096 + wv * 1024;                \
      __builtin_amdgcn_global_load_lds(                                       \
          (const __attribute__((address_space(1))) unsigned int*)gp,          \
          (__attribute__((address_space(3))) unsigned int*)lp, 16, 0, 0);     \
    }                                                                         \
  } while (0)

  STAGE(0, 0);
  __syncthreads();

  int cur = 0;
  for (int jt = 0; jt < 32; ++jt) {
    if (jt + 1 < 32) STAGE(cur ^ 1, jt + 1);

    const int jbase = krange0 + jt * 64;
    const unsigned long long w64a = mrow[0][jt];
    const unsigned long long w64b = mrow[1][jt];
    const unsigned short* lbase = &hTs[cur][0];
#pragma unroll
    for (int k32 = 0; k32 < 2; ++k32) {
      const int kb = k32 * 32 + lg * 8;
      float4 fA = *(const float4*)(f2 + jbase + kb);
      float4 fB = *(const float4*)(f2 + jbase + kb + 4);
      float fv[8] = {fA.x, fA.y, fA.z, fA.w, fB.x, fB.y, fB.z, fB.w};
      bf16x8 afr0, afr1;
      unsigned byA = (unsigned)(w64a >> kb) & 0xffu;
      unsigned byB = (unsigned)(w64b >> kb) & 0xffu;
#pragma unroll
      for (int b = 0; b < 8; ++b) {
        float s0 = f1r[0] + fv[b];
        float t0 = fmaxf(s0, ALPHAV * s0);
        float p0 = ex2(fmaf(t0, L2E, nmv[0]));
        p0 = (byA & (1u << b)) ? p0 : cmv[0];
        afr0[b] = (short)f2bf(p0);
        float s1 = f1r[1] + fv[b];
        float t1 = fmaxf(s1, ALPHAV * s1);
        float p1 = ex2(fmaf(t1, L2E, nmv[1]));
        p1 = (byB & (1u << b)) ? p1 : cmv[1];
        afr1[b] = (short)f2bf(p1);
      }
#pragma unroll
      for (int nf = 0; nf < 8; ++nf) {
        int n = nf * 16 + lm;
        int addr = n * 64 + (kb ^ ((n & 7) << 3));
        bf16x8 bb = *(const bf16x8*)(lbase + addr);
        accA[nf] = __builtin_amdgcn_mfma_f32_16x16x32_bf16(afr0, bb, accA[nf], 0, 0, 0);
        accB[nf] = __builtin_amdgcn_mfma_f32_16x16x32_bf16(afr1, bb, accB[nf], 0, 0, 0);
      }
    }
    __syncthreads();   // drains vmcnt(0): stage(jt+1) done; buffer swap safe
    cur ^= 1;
  }
#undef STAGE

  float* dst = (ks == 0) ? outp : (part + (size_t)(ks - 1) * NN * FOUT);
  const int c0 = cs * 128;
#pragma unroll
  for (int nf = 0; nf < 8; ++nf) {
    int col = c0 + nf * 16 + lm;
#pragma unroll
    for (int e = 0; e < 4; ++e) {
      int rowA = r0 + lg * 4 + e;
      int rowB = r0 + 16 + lg * 4 + e;
      dst[(size_t)rowA * FOUT + col] = accA[nf][e];
      dst[(size_t)rowB * FOUT + col] = accB[nf][e];
    }
  }
}

// ---------------- K5: sum K-partials, scale by 1/rowsum -------------------
__global__ __launch_bounds__(256) void k_fin(
    float* __restrict__ outp, const float* __restrict__ part,
    const float* __restrict__ row_inv)
{
  const int idx4 = blockIdx.x * 256 + threadIdx.x;
  const size_t e = (size_t)idx4 * 4;
  const int i = (int)(e >> 8);
  float4 o  = *(float4*)(outp + e);
  float4 p0 = *(const float4*)(part + e);
  float4 p1 = *(const float4*)(part + (size_t)NN * FOUT + e);
  float4 p2 = *(const float4*)(part + 2 * (size_t)NN * FOUT + e);
  float inv = row_inv[i];
  o.x = (o.x + p0.x + p1.x + p2.x) * inv;
  o.y = (o.y + p0.y + p1.y + p2.y) * inv;
  o.z = (o.z + p0.z + p1.z + p2.z) * inv;
  o.w = (o.w + p0.w + p1.w + p2.w) * inv;
  *(float4*)(outp + e) = o;
}

extern "C" void kernel_launch(void* const* d_in, const int* in_sizes, int n_in,
                              void* d_out, int out_size, void* d_ws, size_t ws_size,
                              hipStream_t stream)
{
  const float* x  = (const float*)d_in[0];
  const int* adj  = (const int*)d_in[1];
  const float* Wm = (const float*)d_in[2];
  const float* aG = (const float*)d_in[3];
  float* outp = (float*)d_out;

  char* w = (char*)d_ws;
  float* h             = (float*)(w + 0);                    // 8 MB
  unsigned short* hT   = (unsigned short*)(w + 8388608);     // 4 MB
  float* f1            = (float*)(w + 12582912);             // 32 KB
  float* f2            = (float*)(w + 12615680);             // 32 KB
  float* row_m         = (float*)(w + 12648448);             // 32 KB
  float* row_inv       = (float*)(w + 12681216);             // 32 KB
  unsigned long long* maskg = (unsigned long long*)(w + 12713984); // 8 MB
  float* part          = (float*)(w + 21102592);             // 24 MB (3 partials)

  hipLaunchKernelGGL(k_gemm_h,  dim3(256),      dim3(128), 0, stream, x, Wm, h, hT);
  hipLaunchKernelGGL(k_f12,     dim3(2048),     dim3(256), 0, stream, h, aG, f1, f2);
  hipLaunchKernelGGL(k_rowstat, dim3(8192),     dim3(256), 0, stream, adj, f1, f2, maskg, row_m, row_inv);
  hipLaunchKernelGGL(k_spmm,    dim3(64, 4, 2), dim3(256), 0, stream, hT, maskg, f1, f2, row_m, outp, part);
  hipLaunchKernelGGL(k_fin,     dim3(2048),     dim3(256), 0, stream, outp, part, row_inv);
}

// Round 3
// 237.239 us; speedup vs baseline: 1.3905x; 1.0858x over previous
//
#include <hip/hip_runtime.h>
#include <hip/hip_bf16.h>
#include <stdint.h>

#define NN 8192
#define FIN 512
#define FOUT 256
#define ALPHAV 0.2f
#define MASKF 9e-15f
#define L2E 1.44269504088896340736f

typedef __attribute__((ext_vector_type(8))) short bf16x8;
typedef __attribute__((ext_vector_type(4))) float f32x4;
typedef unsigned long long u64;

static __device__ __forceinline__ float ex2(float x){
#if __has_builtin(__builtin_amdgcn_exp2f)
  return __builtin_amdgcn_exp2f(x);
#else
  return exp2f(x);
#endif
}
static __device__ __forceinline__ unsigned short f2bf(float f){
  __bf16 b = (__bf16)f;
  return __builtin_bit_cast(unsigned short, b);
}

// ---------------- K1: hT(bf16) = (x@W)^T, fused f1 = h@a1, f2 = h@a2 ------
// 512 blocks x 256 thr (2 waves/SIMD). x read as wave-broadcast float4 (no
// A-LDS). W tile in LDS, staging-linear layout (conflict-free both sides).
// h (fp32) never materialized: f1/f2 reduced in-register from fp32 acc.
__global__ __launch_bounds__(256, 2) void k_gemm_h(
    const float* __restrict__ x, const float* __restrict__ Wm,
    const float* __restrict__ aG, unsigned short* __restrict__ hT,
    float* __restrict__ f1, float* __restrict__ f2)
{
  __shared__ __align__(16) float Bs[4096];   // 16x256 W tile, staging order
  const int t  = threadIdx.x;
  const int rg = t >> 6;          // wave -> 4 rows
  const int cg = t & 63;          // lane -> 4 cols
  const int i0 = blockIdx.x * 16;
  const int wk = t >> 4;          // staging k-row 0..15
  const int wc = (t & 15) * 4;    // staging col 0..60 within 64-col section

  float acc[4][4];
#pragma unroll
  for (int r = 0; r < 4; ++r)
#pragma unroll
    for (int c = 0; c < 4; ++c) acc[r][c] = 0.f;

  const float* xrow[4];
#pragma unroll
  for (int r = 0; r < 4; ++r) xrow[r] = x + (size_t)(i0 + rg * 4 + r) * FIN;

  for (int k0 = 0; k0 < FIN; k0 += 16) {
    __syncthreads();
    // stage W[k0..k0+15][0..255]: element (kk=wk, col=q*64+wc+j) -> Bs[q*1024+t*4+j]
#pragma unroll
    for (int q = 0; q < 4; ++q) {
      float4 wv4 = *(const float4*)(Wm + (size_t)(k0 + wk) * FOUT + q * 64 + wc);
      *(float4*)(&Bs[q * 1024 + t * 4]) = wv4;
    }
    __syncthreads();
#pragma unroll
    for (int q = 0; q < 4; ++q) {
      float4 xa[4];
#pragma unroll
      for (int r = 0; r < 4; ++r) xa[r] = *(const float4*)(xrow[r] + k0 + q * 4);
#pragma unroll
      for (int k2 = 0; k2 < 4; ++k2) {
        const int kk = q * 4 + k2;
        // inverse map: (kk, col=cg*4+j) at Bs[(cg>>4)*1024 + kk*64 + (cg&15)*4 + j]
        float4 bv = *(const float4*)(&Bs[(cg >> 4) * 1024 + kk * 64 + (cg & 15) * 4]);
        float bb4[4] = {bv.x, bv.y, bv.z, bv.w};
#pragma unroll
        for (int r = 0; r < 4; ++r) {
          float ar = (k2 == 0) ? xa[r].x : (k2 == 1) ? xa[r].y : (k2 == 2) ? xa[r].z : xa[r].w;
#pragma unroll
          for (int c = 0; c < 4; ++c) acc[r][c] = fmaf(ar, bb4[c], acc[r][c]);
        }
      }
    }
  }
  // hT (transposed, bf16): 4 rows packed per 8B store
#pragma unroll
  for (int c = 0; c < 4; ++c) {
    int col = cg * 4 + c;
    ushort4 u;
    u.x = f2bf(acc[0][c]); u.y = f2bf(acc[1][c]);
    u.z = f2bf(acc[2][c]); u.w = f2bf(acc[3][c]);
    *(ushort4*)(hT + (size_t)col * NN + i0 + rg * 4) = u;
  }
  // fused f1/f2: per-row dot over this lane's 4 cols, wave shfl reduce
  float4 a1 = *(const float4*)(aG + cg * 4);
  float4 a2 = *(const float4*)(aG + FOUT + cg * 4);
#pragma unroll
  for (int r = 0; r < 4; ++r) {
    float s1 = acc[r][0]*a1.x + acc[r][1]*a1.y + acc[r][2]*a1.z + acc[r][3]*a1.w;
    float s2 = acc[r][0]*a2.x + acc[r][1]*a2.y + acc[r][2]*a2.z + acc[r][3]*a2.w;
#pragma unroll
    for (int off = 32; off > 0; off >>= 1) {
      s1 += __shfl_xor(s1, off);
      s2 += __shfl_xor(s2, off);
    }
    if (cg == 0) { f1[i0 + rg * 4 + r] = s1; f2[i0 + rg * 4 + r] = s2; }
  }
}

// ---------------- K3: per-row max + exp-sum + adj->bitmask ----------------
__global__ __launch_bounds__(256) void k_rowstat(
    const int* __restrict__ adj, const float* __restrict__ f1,
    const float* __restrict__ f2, u64* __restrict__ maskg,
    float* __restrict__ row_m, float* __restrict__ row_inv)
{
  __shared__ float red[8];
  const int i = blockIdx.x;
  const int t = threadIdx.x;
  const int wv = t >> 6;
  const int l = t & 63;
  const float f1i = f1[i];
  const int* arow = adj + (size_t)i * NN + wv * 2048;
  const float* f2w = f2 + wv * 2048;
  unsigned int bits = 0;
  float mloc = -3.0e38f;
  float f2loc[32];
#pragma unroll
  for (int it = 0; it < 32; ++it) {
    int av = arow[it * 64 + l];
    bool bit = av > 0;
    u64 bal = __ballot(bit);
    if (l == 0) maskg[(size_t)i * 128 + wv * 32 + it] = bal;
    float f2j = f2w[it * 64 + l];
    f2loc[it] = f2j;
    float s = f1i + f2j;
    float ls = fmaxf(s, ALPHAV * s);
    float e = bit ? ls : MASKF;
    mloc = fmaxf(mloc, e);
    bits |= (bit ? 1u : 0u) << it;
  }
#pragma unroll
  for (int off = 32; off > 0; off >>= 1) mloc = fmaxf(mloc, __shfl_xor(mloc, off));
  if (l == 0) red[wv] = mloc;
  __syncthreads();
  const float m = fmaxf(fmaxf(red[0], red[1]), fmaxf(red[2], red[3]));
  const float nm = -m * L2E;
  const float cm = ex2(fmaf(MASKF, L2E, nm));
  float sl = 0.f;
#pragma unroll
  for (int it = 0; it < 32; ++it) {
    float s = f1i + f2loc[it];
    float ls = fmaxf(s, ALPHAV * s);
    float pe = ex2(fmaf(ls, L2E, nm));
    sl += ((bits >> it) & 1u) ? pe : cm;
  }
#pragma unroll
  for (int off = 32; off > 0; off >>= 1) sl += __shfl_xor(sl, off);
  __syncthreads();
  if (l == 0) red[4 + wv] = sl;
  __syncthreads();
  if (t == 0) {
    float tot = red[4] + red[5] + red[6] + red[7];
    row_m[i] = m;
    row_inv[i] = 1.f / tot;
  }
}

// ---------------- K4: fused P-regen + (P @ h) via bf16 MFMA ---------------
// grid (32, 8, 2): BM=256 (8 waves), ks = 1024-j slice, cs = 128-col half.
// 512 blocks = 2/CU = 4 waves/SIMD. f2 slice pre-scaled in LDS; masks
// register-prefetched one jt ahead (jt unrolled x2, named regs/buffers);
// hT double-buffered via global_load_lds with pre-swizzled source.
__global__ __launch_bounds__(512, 4) void k_spmm(
    const unsigned short* __restrict__ hTg,
    const u64* __restrict__ maskg,
    const float* __restrict__ f1, const float* __restrict__ f2,
    const float* __restrict__ row_m,
    float* __restrict__ outp, float* __restrict__ part)
{
  __shared__ __align__(16) unsigned short hTs0[128 * 64]; // 16 KB
  __shared__ __align__(16) unsigned short hTs1[128 * 64]; // 16 KB
  __shared__ __align__(16) float f2s[1024];               // 4 KB, pre-scaled
  const int t  = threadIdx.x;
  const int wv = t >> 6;
  const int l  = t & 63;
  const int lg = l >> 4;
  const int lm = l & 15;
  const int bx = blockIdx.x;
  const int ks = blockIdx.y;
  const int cs = blockIdx.z;
  const int r0w = bx * 256 + wv * 32;

  // f2 slice -> LDS, pre-scaled by L2E
  {
    float2 v = *(const float2*)(f2 + ks * 1024 + t * 2);
    f2s[t * 2 + 0] = v.x * L2E;
    f2s[t * 2 + 1] = v.y * L2E;
  }

  // per-row constants (af=0 rows rA, af=1 rows rB)
  const int rA = r0w + lm, rB = r0w + 16 + lm;
  const float nmA = -row_m[rA] * L2E, nmB = -row_m[rB] * L2E;
  const float base0 = fmaf(f1[rA], L2E, nmA), base1 = fmaf(f1[rB], L2E, nmB);
  const float c20 = nmA * (1.f - ALPHAV),     c21 = nmB * (1.f - ALPHAV);
  const float mc0 = fmaf(MASKF, L2E, nmA),    mc1 = fmaf(MASKF, L2E, nmB);
  const u64* mrowA = maskg + (size_t)rA * 128 + ks * 16;
  const u64* mrowB = maskg + (size_t)rB * 128 + ks * 16;

  f32x4 accA[8], accB[8];
#pragma unroll
  for (int nf = 0; nf < 8; ++nf)
#pragma unroll
    for (int e = 0; e < 4; ++e) { accA[nf][e] = 0.f; accB[nf][e] = 0.f; }

  // staging: thread t -> n = c*64 + (t>>3), 16B at swizzled source k
  const int sk = ((t & 7) * 8) ^ (((t >> 3) & 7) << 3);
  const size_t grow0 = (size_t)(cs * 128 + (t >> 3)) * NN + ks * 1024 + sk;

#define STAGE(DST, JT)                                                        \
  do {                                                                        \
    _Pragma("unroll")                                                         \
    for (int c = 0; c < 2; ++c) {                                             \
      const unsigned short* gp = hTg + grow0 + (size_t)c * 64 * NN + (JT) * 64;\
      char* lp = (char*)(DST) + c * 8192 + wv * 1024;                         \
      __builtin_amdgcn_global_load_lds(                                       \
          (const __attribute__((address_space(1))) unsigned int*)gp,          \
          (__attribute__((address_space(3))) unsigned int*)lp, 16, 0, 0);     \
    }                                                                         \
  } while (0)

#define COMPUTE_PHASE(LB, WA, WB, JT)                                         \
  do {                                                                        \
    _Pragma("unroll")                                                         \
    for (int k32 = 0; k32 < 2; ++k32) {                                       \
      const int kb = k32 * 32 + lg * 8;                                       \
      float4 fA = *(const float4*)(&f2s[(JT) * 64 + kb]);                     \
      float4 fB = *(const float4*)(&f2s[(JT) * 64 + kb + 4]);                 \
      float fv[8] = {fA.x, fA.y, fA.z, fA.w, fB.x, fB.y, fB.z, fB.w};         \
      unsigned byA = (unsigned)((WA) >> kb) & 0xffu;                          \
      unsigned byB = (unsigned)((WB) >> kb) & 0xffu;                          \
      bf16x8 afr0, afr1;                                                      \
      _Pragma("unroll")                                                       \
      for (int b = 0; b < 8; ++b) {                                           \
        float u0 = base0 + fv[b];                                             \
        float w0 = fmaxf(u0, fmaf(ALPHAV, u0, c20));                          \
        w0 = (byA & (1u << b)) ? w0 : mc0;                                    \
        afr0[b] = (short)f2bf(ex2(w0));                                       \
        float u1 = base1 + fv[b];                                             \
        float w1 = fmaxf(u1, fmaf(ALPHAV, u1, c21));                          \
        w1 = (byB & (1u << b)) ? w1 : mc1;                                    \
        afr1[b] = (short)f2bf(ex2(w1));                                       \
      }                                                                       \
      _Pragma("unroll")                                                       \
      for (int nf = 0; nf < 8; ++nf) {                                        \
        int n = nf * 16 + lm;                                                 \
        int addr = n * 64 + (kb ^ ((n & 7) << 3));                            \
        bf16x8 bb = *(const bf16x8*)((LB) + addr);                            \
        accA[nf] = __builtin_amdgcn_mfma_f32_16x16x32_bf16(afr0, bb, accA[nf], 0, 0, 0); \
        accB[nf] = __builtin_amdgcn_mfma_f32_16x16x32_bf16(afr1, bb, accB[nf], 0, 0, 0); \
      }                                                                       \
    }                                                                         \
  } while (0)

  STAGE(hTs0, 0);
  u64 mEa = mrowA[0], mEb = mrowB[0];
  __syncthreads();   // f2s writes + stage(0) complete

  u64 mOa, mOb;
  for (int jp = 0; jp < 8; ++jp) {
    const int jt = jp * 2;
    STAGE(hTs1, jt + 1);
    mOa = mrowA[jt + 1]; mOb = mrowB[jt + 1];
    COMPUTE_PHASE(hTs0, mEa, mEb, jt);
    __syncthreads();   // hTs1 ready; hTs0 free
    if (jp < 7) {
      STAGE(hTs0, jt + 2);
      mEa = mrowA[jt + 2]; mEb = mrowB[jt + 2];
    }
    COMPUTE_PHASE(hTs1, mOa, mOb, jt + 1);
    __syncthreads();   // hTs0 ready; hTs1 free
  }
#undef STAGE
#undef COMPUTE_PHASE

  float* dst = (ks == 0) ? outp : (part + (size_t)(ks - 1) * NN * FOUT);
  const int c0 = cs * 128;
#pragma unroll
  for (int nf = 0; nf < 8; ++nf) {
    int col = c0 + nf * 16 + lm;
#pragma unroll
    for (int e = 0; e < 4; ++e) {
      int rowA = r0w + lg * 4 + e;
      int rowB = r0w + 16 + lg * 4 + e;
      dst[(size_t)rowA * FOUT + col] = accA[nf][e];
      dst[(size_t)rowB * FOUT + col] = accB[nf][e];
    }
  }
}

// ---------------- K5: sum 7 K-partials, scale by 1/rowsum -----------------
__global__ __launch_bounds__(256) void k_fin(
    float* __restrict__ outp, const float* __restrict__ part,
    const float* __restrict__ row_inv)
{
  const int idx4 = blockIdx.x * 256 + threadIdx.x;
  const size_t e = (size_t)idx4 * 4;
  const int i = (int)(e >> 8);
  float4 o = *(float4*)(outp + e);
#pragma unroll
  for (int p = 0; p < 7; ++p) {
    float4 pv = *(const float4*)(part + (size_t)p * NN * FOUT + e);
    o.x += pv.x; o.y += pv.y; o.z += pv.z; o.w += pv.w;
  }
  float inv = row_inv[i];
  o.x *= inv; o.y *= inv; o.z *= inv; o.w *= inv;
  *(float4*)(outp + e) = o;
}

extern "C" void kernel_launch(void* const* d_in, const int* in_sizes, int n_in,
                              void* d_out, int out_size, void* d_ws, size_t ws_size,
                              hipStream_t stream)
{
  const float* x  = (const float*)d_in[0];
  const int* adj  = (const int*)d_in[1];
  const float* Wm = (const float*)d_in[2];
  const float* aG = (const float*)d_in[3];
  float* outp = (float*)d_out;

  char* w = (char*)d_ws;
  unsigned short* hT = (unsigned short*)(w + 0);             // 4 MB
  float* f1          = (float*)(w + 4194304);                // 32 KB
  float* f2          = (float*)(w + 4227072);                // 32 KB
  float* row_m       = (float*)(w + 4259840);                // 32 KB
  float* row_inv     = (float*)(w + 4292608);                // 32 KB
  u64*   maskg       = (u64*)(w + 4325376);                  // 8 MB
  float* part        = (float*)(w + 12713984);               // 56 MB (7 partials)

  hipLaunchKernelGGL(k_gemm_h,  dim3(512),      dim3(256), 0, stream, x, Wm, aG, hT, f1, f2);
  hipLaunchKernelGGL(k_rowstat, dim3(8192),     dim3(256), 0, stream, adj, f1, f2, maskg, row_m, row_inv);
  hipLaunchKernelGGL(k_spmm,    dim3(32, 8, 2), dim3(512), 0, stream, hT, maskg, f1, f2, row_m, outp, part);
  hipLaunchKernelGGL(k_fin,     dim3(2048),     dim3(256), 0, stream, outp, part, row_inv);
}